// Round 1
// baseline (227.137 us; speedup 1.0000x reference)
//
#include <hip/hip_runtime.h>

#define NN  1024
#define EMB 128
#define HID 128

typedef __attribute__((ext_vector_type(4))) float float4v;
typedef __attribute__((ext_vector_type(8))) float float8v;
typedef __attribute__((ext_vector_type(8))) short short8;
typedef __attribute__((ext_vector_type(4))) __bf16 bf16x4;
typedef __attribute__((ext_vector_type(8))) __bf16 bf16x8;

__device__ __forceinline__ short8 to_bf16x8(float4v a, float4v b) {
  float8v f = {a[0], a[1], a[2], a[3], b[0], b[1], b[2], b[3]};
  bf16x8 r = __builtin_convertvector(f, bf16x8);   // v_cvt_pk_bf16_f32 x4
  return __builtin_bit_cast(short8, r);
}

__device__ __forceinline__ void store_bf16x4(short* p, float4v v) {
  bf16x4 r = __builtin_convertvector(v, bf16x4);
  *(bf16x4*)p = r;
}

// tanh-form GELU, vectorized; ONE v_rcp per 4 elements via shared reciprocal.
// d_i = 1+2^y >= 1, |x|<4.5 => product < 2^80: no overflow.
__device__ __forceinline__ float4v gelu4(float4v x) {
  float4v x2 = x * x;
  float4v t = x2 * 0.1029432f + 2.3022086f;   // 2*sqrt(2/pi)*log2e*(1+0.044715x^2)
  float4v y = x * t;
  float4v e;
  e[0] = __builtin_amdgcn_exp2f(y[0]);
  e[1] = __builtin_amdgcn_exp2f(y[1]);
  e[2] = __builtin_amdgcn_exp2f(y[2]);
  e[3] = __builtin_amdgcn_exp2f(y[3]);
  float4v d = e + 1.0f;
  float p01 = d[0] * d[1];
  float p23 = d[2] * d[3];
  float rall = __builtin_amdgcn_rcpf(p01 * p23);
  float r01 = p23 * rall;                     // 1/(d0*d1)
  float r23 = p01 * rall;                     // 1/(d2*d3)
  float4v rv;
  rv[0] = d[1] * r01;
  rv[1] = d[0] * r01;
  rv[2] = d[3] * r23;
  rv[3] = d[2] * r23;
  return x - x * rv;                          // x*sigmoid(2*inner)
}

__device__ __forceinline__ float4v mfma16(short8 a, short8 b, float4v c) {
  return __builtin_amdgcn_mfma_f32_16x16x32_bf16(a, b, c, 0, 0, 0);
}

// ---------------------------------------------------------------------------
// prep: blocks 0..127  -> Abuf[j, hh*64..+63] = z1[j,:]·W1a[g,:] + b1 (16 j x 64 g)
//       blocks 128..255-> Bbuf[i, hh*64..+63] = z2[i,:]·W1b[g,:]
//       blocks 256..263-> W2f: bf16(W2) pre-swizzled into MFMA frag order,
//                         grouped by PASS-HALF: half p = g-range [64p, 64p+64),
//                         each half contiguous 16 KB so fused can stage halves.
// ---------------------------------------------------------------------------
__global__ __launch_bounds__(256)
void prep_kernel(const float* __restrict__ z1, const float* __restrict__ z2,
                 const float* __restrict__ W1, const float* __restrict__ b1,
                 const float* __restrict__ W2,
                 float* __restrict__ Abuf, float* __restrict__ Bbuf,
                 unsigned short* __restrict__ W2f) {
  int blk = blockIdx.x, tid = threadIdx.x;
  if (blk < 256) {
    int which = blk >> 7;                 // 0: A (z1,W1a,+b1)  1: B (z2,W1b)
    int j0 = ((blk & 127) >> 1) << 4;     // 16-row tile
    int hh = blk & 1;                     // h-half (64 g)
    const float* z = which ? z2 : z1;
    __shared__ __align__(16) short zf[4 * 64 * 8];    // 4 KB  z a-frags
    __shared__ __align__(16) short w1f[16 * 64 * 8];  // 16 KB W1 b-frags

#pragma unroll
    for (int p = 0; p < 2; ++p) {
      int u = p * 256 + tid;
      int row = u >> 5;                   // 0..15
      int c = (u & 31) * 4;               // 0..124
      float4v v = *(const float4v*)(z + (j0 + row) * EMB + c);
      int kt = c >> 5;
      int lane = ((c >> 3) & 3) * 16 + row;
      store_bf16x4(zf + (kt * 64 + lane) * 8 + (c & 7), v);
    }
    {
      const float* wbase = W1 + (hh * 64) * (2 * EMB) + which * EMB;
#pragma unroll
      for (int p = 0; p < 8; ++p) {
        int u = p * 256 + tid;
        int grow = u >> 5;                // 0..63
        int c = (u & 31) * 4;
        float4v v = *(const float4v*)(wbase + grow * (2 * EMB) + c);
        int kt = c >> 5;
        int ntl = grow >> 4;              // 0..3
        int lane = ((c >> 3) & 3) * 16 + (grow & 15);
        store_bf16x4(w1f + ((kt * 4 + ntl) * 64 + lane) * 8 + (c & 7), v);
      }
    }
    __syncthreads();

    int w = tid >> 6, l = tid & 63, r = l & 15, q = l >> 4;
    float4v acc = {};
#pragma unroll
    for (int kt = 0; kt < 4; ++kt) {
      short8 az = *(const short8*)(zf + (kt * 64 + l) * 8);
      short8 bf = *(const short8*)(w1f + ((kt * 4 + w) * 64 + l) * 8);
      acc = mfma16(az, bf, acc);
    }
    int gg = hh * 64 + w * 16 + r;
    float ba = which ? 0.0f : b1[gg];
    float* dstp = which ? Bbuf : Abuf;
#pragma unroll
    for (int reg = 0; reg < 4; ++reg)
      dstp[(j0 + q * 4 + reg) * HID + gg] = acc[reg] + ba;
  } else {
    // W2f swizzle: coalesced dwordx4 reads, scattered bf16 writes.
    // New layout: half p (p = nt>>2) occupies [p*8192, p*8192+8192) shorts,
    // within a half: ((kt*4 + (nt&3))*64 + lane)*8 + (h&7).
    int s0 = (blk - 256) * 2048 + tid * 8;
    float4v v0 = *(const float4v*)(W2 + s0);
    float4v v1 = *(const float4v*)(W2 + s0 + 4);
    float vals[8] = {v0[0], v0[1], v0[2], v0[3], v1[0], v1[1], v1[2], v1[3]};
#pragma unroll
    for (int j = 0; j < 8; ++j) {
      int s = s0 + j;
      int g = s >> 7;
      int h = s & 127;
      int kt = h >> 5;
      int nt = g >> 4;
      int p = nt >> 2;
      int lane = ((h >> 3) & 3) * 16 + (g & 15);
      int dst = p * 8192 + ((kt * 4 + (nt & 3)) * 64 + lane) * 8 + (h & 7);
      unsigned u = __float_as_uint(vals[j]);
      W2f[dst] = (unsigned short)((u + 0x7FFFu + ((u >> 16) & 1u)) >> 16);  // RNE
    }
  }
}

// ---------------------------------------------------------------------------
// main: one block = 8i x 16j tile, 256 threads (4 waves), wave owns 2 i-rows.
// Swapped operands: D[g][pair] = W2 · h1^T.
// TWO-PASS g-split with HALF-STAGED LDS: s_w2 is now 16 KB and holds only the
// current pass's W2 fragments; half 1 is re-staged between passes with the
// global loads issued BEFORE the pass-0 epilogue (latency hides under 8x
// gelu4 of VALU work). 16 KB LDS + ~96 unified regs => 5 blocks/CU
// (launch_bounds(256,5)), up from ~4: more resident waves fill the vmcnt/
// lgkm stall holes (VALUBusy 68% -> target >80%). Numerics untouched.
// ---------------------------------------------------------------------------
__global__ __launch_bounds__(256, 5)
void fused_mlp_kernel(const float* __restrict__ Abuf, const float* __restrict__ Bbuf,
                      const float* __restrict__ W2f4,  // packed bf16 frags, half-major
                      const float* __restrict__ b2, const float* __restrict__ W3,
                      const float* __restrict__ b3, float* __restrict__ out) {
  __shared__ __align__(16) short s_w2[64 * 128];  // 16 KB, one pass-half

  int tid = threadIdx.x;
  int w = tid >> 6, l = tid & 63, r = l & 15, q = l >> 4;
  int bi = (blockIdx.x >> 6) << 3;
  int bj = (blockIdx.x & 63) << 4;

  const float* Ap  = Abuf + (bj + r) * HID + q * 8;       // A'[j=bj+r]
  const float* Bp0 = Bbuf + (bi + 2 * w) * HID + q * 8;   // B[i0]
  const float* Bp1 = Bp0 + HID;                           // B[i1]

  const float4v* wsrc = (const float4v*)W2f4;
  float4v* dstv = (float4v*)s_w2;

  // issue half-0 staging loads + kt=0 A/B preloads before the barrier
  float4v wst[4];
#pragma unroll
  for (int t = 0; t < 4; ++t) wst[t] = wsrc[tid + t * 256];

  float4v a0  = *(const float4v*)(Ap);
  float4v a1  = *(const float4v*)(Ap + 4);
  float4v b00 = *(const float4v*)(Bp0);
  float4v b01 = *(const float4v*)(Bp0 + 4);
  float4v b10 = *(const float4v*)(Bp1);
  float4v b11 = *(const float4v*)(Bp1 + 4);

#pragma unroll
  for (int t = 0; t < 4; ++t) dstv[tid + t * 256] = wst[t];

  short8 afs[4][2];                 // h1 frag stash: [kt][p], 32 VGPRs
  float4v s0 = {0.f, 0.f, 0.f, 0.f};
  float4v s1 = {0.f, 0.f, 0.f, 0.f};
  float4v acc[2][4];

  __syncthreads();

  // ---------------- pass 0: g in [0,64) ----------------
#pragma unroll
  for (int nt = 0; nt < 4; ++nt) {
    float4v bv = *(const float4v*)(b2 + nt * 16 + q * 4);
    acc[0][nt] = bv;
    acc[1][nt] = bv;
  }

#pragma unroll
  for (int kt = 0; kt < 4; ++kt) {
    float4v ca0 = a0, ca1 = a1, cb00 = b00, cb01 = b01, cb10 = b10, cb11 = b11;
    if (kt < 3) {                       // issue next-kt loads before gelu chain
      int off = (kt + 1) * 32;
      a0  = *(const float4v*)(Ap + off);
      a1  = *(const float4v*)(Ap + off + 4);
      b00 = *(const float4v*)(Bp0 + off);
      b01 = *(const float4v*)(Bp0 + off + 4);
      b10 = *(const float4v*)(Bp1 + off);
      b11 = *(const float4v*)(Bp1 + off + 4);
    }
    short8 af0 = to_bf16x8(gelu4(ca0 + cb00), gelu4(ca1 + cb01));
    short8 af1 = to_bf16x8(gelu4(ca0 + cb10), gelu4(ca1 + cb11));
    afs[kt][0] = af0;
    afs[kt][1] = af1;

    const short8* wrow = (const short8*)s_w2 + kt * 256 + l;
#pragma unroll
    for (int nt = 0; nt < 4; ++nt) {
      short8 wf = wrow[nt * 64];        // stride-16B, conflict-free
      acc[0][nt] = mfma16(wf, af0, acc[0][nt]);
      acc[1][nt] = mfma16(wf, af1, acc[1][nt]);
    }
  }

  // issue half-1 staging loads now; their latency hides under the epilogue
#pragma unroll
  for (int t = 0; t < 4; ++t) wst[t] = wsrc[1024 + tid + t * 256];

#pragma unroll
  for (int nt = 0; nt < 4; ++nt) {
    float4v wv = *(const float4v*)(W3 + nt * 16 + q * 4);
    s0 = s0 + gelu4(acc[0][nt]) * wv;
    s1 = s1 + gelu4(acc[1][nt]) * wv;
  }

  // ---------------- re-stage LDS with half 1 ----------------
  __syncthreads();                      // all pass-0 reads of s_w2 done
#pragma unroll
  for (int t = 0; t < 4; ++t) dstv[tid + t * 256] = wst[t];
  __syncthreads();                      // half 1 visible

  // ---------------- pass 1: g in [64,128) — stash replay, no gelu/VMEM ----
#pragma unroll
  for (int nt = 0; nt < 4; ++nt) {
    float4v bv = *(const float4v*)(b2 + (nt + 4) * 16 + q * 4);
    acc[0][nt] = bv;
    acc[1][nt] = bv;
  }
#pragma unroll
  for (int kt = 0; kt < 4; ++kt) {
    short8 af0 = afs[kt][0];
    short8 af1 = afs[kt][1];
    const short8* wrow = (const short8*)s_w2 + kt * 256 + l;
#pragma unroll
    for (int nt = 0; nt < 4; ++nt) {
      short8 wf = wrow[nt * 64];
      acc[0][nt] = mfma16(wf, af0, acc[0][nt]);
      acc[1][nt] = mfma16(wf, af1, acc[1][nt]);
    }
  }
#pragma unroll
  for (int nt = 0; nt < 4; ++nt) {
    float4v wv = *(const float4v*)(W3 + (nt + 4) * 16 + q * 4);
    s0 = s0 + gelu4(acc[0][nt]) * wv;
    s1 = s1 + gelu4(acc[1][nt]) * wv;
  }

  // reduce + store
  float bias3 = b3[0];
  float sc0 = s0[0] + s0[1] + s0[2] + s0[3];
  float sc1 = s1[0] + s1[1] + s1[2] + s1[3];
  sc0 += __shfl_xor(sc0, 16, 64);
  sc0 += __shfl_xor(sc0, 32, 64);
  sc1 += __shfl_xor(sc1, 16, 64);
  sc1 += __shfl_xor(sc1, 32, 64);
  if (l < 16) {
    out[(bi + 2 * w) * NN + bj + l]     = sc0 + bias3;
    out[(bi + 2 * w + 1) * NN + bj + l] = sc1 + bias3;
  }
}

extern "C" void kernel_launch(void* const* d_in, const int* in_sizes, int n_in,
                              void* d_out, int out_size, void* d_ws, size_t ws_size,
                              hipStream_t stream) {
  const float* z1 = (const float*)d_in[0];
  const float* z2 = (const float*)d_in[1];
  const float* W1 = (const float*)d_in[2];
  const float* b1 = (const float*)d_in[3];
  const float* W2 = (const float*)d_in[4];
  const float* b2 = (const float*)d_in[5];
  const float* W3 = (const float*)d_in[6];
  const float* b3 = (const float*)d_in[7];
  float* out = (float*)d_out;

  float* Abuf = (float*)d_ws;                                // 512 KB
  float* Bbuf = Abuf + NN * HID;                             // 512 KB
  unsigned short* W2f = (unsigned short*)(Bbuf + NN * HID);  // 32 KB

  prep_kernel<<<264, 256, 0, stream>>>(z1, z2, W1, b1, W2, Abuf, Bbuf, W2f);
  fused_mlp_kernel<<<(NN / 8) * (NN / 16), 256, 0, stream>>>(
      Abuf, Bbuf, (const float*)W2f, b2, W3, b3, out);
}

// Round 2
// 158.880 us; speedup vs baseline: 1.4296x; 1.4296x over previous
//
#include <hip/hip_runtime.h>

#define NN  1024
#define EMB 128
#define HID 128

typedef __attribute__((ext_vector_type(4))) float float4v;
typedef __attribute__((ext_vector_type(8))) float float8v;
typedef __attribute__((ext_vector_type(8))) short short8;
typedef __attribute__((ext_vector_type(4))) __bf16 bf16x4;
typedef __attribute__((ext_vector_type(8))) __bf16 bf16x8;

__device__ __forceinline__ short8 to_bf16x8(float4v a, float4v b) {
  float8v f = {a[0], a[1], a[2], a[3], b[0], b[1], b[2], b[3]};
  bf16x8 r = __builtin_convertvector(f, bf16x8);   // v_cvt_pk_bf16_f32 x4
  return __builtin_bit_cast(short8, r);
}

__device__ __forceinline__ void store_bf16x4(short* p, float4v v) {
  bf16x4 r = __builtin_convertvector(v, bf16x4);
  *(bf16x4*)p = r;
}

// tanh-form GELU, vectorized; ONE v_rcp per 4 elements via shared reciprocal.
// d_i = 1+2^y >= 1, |x|<4.5 => product < 2^80: no overflow.
__device__ __forceinline__ float4v gelu4(float4v x) {
  float4v x2 = x * x;
  float4v t = x2 * 0.1029432f + 2.3022086f;   // 2*sqrt(2/pi)*log2e*(1+0.044715x^2)
  float4v y = x * t;
  float4v e;
  e[0] = __builtin_amdgcn_exp2f(y[0]);
  e[1] = __builtin_amdgcn_exp2f(y[1]);
  e[2] = __builtin_amdgcn_exp2f(y[2]);
  e[3] = __builtin_amdgcn_exp2f(y[3]);
  float4v d = e + 1.0f;
  float p01 = d[0] * d[1];
  float p23 = d[2] * d[3];
  float rall = __builtin_amdgcn_rcpf(p01 * p23);
  float r01 = p23 * rall;                     // 1/(d0*d1)
  float r23 = p01 * rall;                     // 1/(d2*d3)
  float4v rv;
  rv[0] = d[1] * r01;
  rv[1] = d[0] * r01;
  rv[2] = d[3] * r23;
  rv[3] = d[2] * r23;
  return x - x * rv;                          // x*sigmoid(2*inner)
}

__device__ __forceinline__ float4v mfma16(short8 a, short8 b, float4v c) {
  return __builtin_amdgcn_mfma_f32_16x16x32_bf16(a, b, c, 0, 0, 0);
}

// ---------------------------------------------------------------------------
// prep: blocks 0..127  -> Abuf[j, hh*64..+63] = z1[j,:]·W1a[g,:] + b1 (16 j x 64 g)
//       blocks 128..255-> Bbuf[i, hh*64..+63] = z2[i,:]·W1b[g,:]
//       blocks 256..263-> W2f: bf16(W2) pre-swizzled into MFMA frag order,
//                         grouped by PASS-HALF: half p = g-range [64p, 64p+64),
//                         each half contiguous 16 KB.
// ---------------------------------------------------------------------------
__global__ __launch_bounds__(256)
void prep_kernel(const float* __restrict__ z1, const float* __restrict__ z2,
                 const float* __restrict__ W1, const float* __restrict__ b1,
                 const float* __restrict__ W2,
                 float* __restrict__ Abuf, float* __restrict__ Bbuf,
                 unsigned short* __restrict__ W2f) {
  int blk = blockIdx.x, tid = threadIdx.x;
  if (blk < 256) {
    int which = blk >> 7;                 // 0: A (z1,W1a,+b1)  1: B (z2,W1b)
    int j0 = ((blk & 127) >> 1) << 4;     // 16-row tile
    int hh = blk & 1;                     // h-half (64 g)
    const float* z = which ? z2 : z1;
    __shared__ __align__(16) short zf[4 * 64 * 8];    // 4 KB  z a-frags
    __shared__ __align__(16) short w1f[16 * 64 * 8];  // 16 KB W1 b-frags

#pragma unroll
    for (int p = 0; p < 2; ++p) {
      int u = p * 256 + tid;
      int row = u >> 5;                   // 0..15
      int c = (u & 31) * 4;               // 0..124
      float4v v = *(const float4v*)(z + (j0 + row) * EMB + c);
      int kt = c >> 5;
      int lane = ((c >> 3) & 3) * 16 + row;
      store_bf16x4(zf + (kt * 64 + lane) * 8 + (c & 7), v);
    }
    {
      const float* wbase = W1 + (hh * 64) * (2 * EMB) + which * EMB;
#pragma unroll
      for (int p = 0; p < 8; ++p) {
        int u = p * 256 + tid;
        int grow = u >> 5;                // 0..63
        int c = (u & 31) * 4;
        float4v v = *(const float4v*)(wbase + grow * (2 * EMB) + c);
        int kt = c >> 5;
        int ntl = grow >> 4;              // 0..3
        int lane = ((c >> 3) & 3) * 16 + (grow & 15);
        store_bf16x4(w1f + ((kt * 4 + ntl) * 64 + lane) * 8 + (c & 7), v);
      }
    }
    __syncthreads();

    int w = tid >> 6, l = tid & 63, r = l & 15, q = l >> 4;
    float4v acc = {};
#pragma unroll
    for (int kt = 0; kt < 4; ++kt) {
      short8 az = *(const short8*)(zf + (kt * 64 + l) * 8);
      short8 bf = *(const short8*)(w1f + ((kt * 4 + w) * 64 + l) * 8);
      acc = mfma16(az, bf, acc);
    }
    int gg = hh * 64 + w * 16 + r;
    float ba = which ? 0.0f : b1[gg];
    float* dstp = which ? Bbuf : Abuf;
#pragma unroll
    for (int reg = 0; reg < 4; ++reg)
      dstp[(j0 + q * 4 + reg) * HID + gg] = acc[reg] + ba;
  } else {
    // W2f swizzle: coalesced dwordx4 reads, scattered bf16 writes.
    // Half-major layout: half p = nt>>2 at [p*8192, p*8192+8192) shorts,
    // within a half: ((kt*4 + (nt&3))*64 + lane)*8 + (h&7).
    int s0 = (blk - 256) * 2048 + tid * 8;
    float4v v0 = *(const float4v*)(W2 + s0);
    float4v v1 = *(const float4v*)(W2 + s0 + 4);
    float vals[8] = {v0[0], v0[1], v0[2], v0[3], v1[0], v1[1], v1[2], v1[3]};
#pragma unroll
    for (int j = 0; j < 8; ++j) {
      int s = s0 + j;
      int g = s >> 7;
      int h = s & 127;
      int kt = h >> 5;
      int nt = g >> 4;
      int p = nt >> 2;
      int lane = ((h >> 3) & 3) * 16 + (g & 15);
      int dst = p * 8192 + ((kt * 4 + (nt & 3)) * 64 + lane) * 8 + (h & 7);
      unsigned u = __float_as_uint(vals[j]);
      W2f[dst] = (unsigned short)((u + 0x7FFFu + ((u >> 16) & 1u)) >> 16);  // RNE
    }
  }
}

// ---------------------------------------------------------------------------
// main: one block = 8i x 16j tile, 256 threads (4 waves), wave owns 2 i-rows.
// Swapped operands: D[g][pair] = W2 · h1^T.
// TWO-PASS g-split, full 32 KB W2 resident (no mid-kernel barriers).
// Register-pressure diet vs round 0 (which sat at ~160 regs -> 3 waves/EU):
//   * W2 staged by __builtin_amdgcn_global_load_lds (async, ZERO VGPRs;
//     round 0 round-tripped 32 KB through 8 float4v temps),
//   * explicit next-kt A/B prefetch registers dropped (-24 VGPRs); at
//     4 waves/EU cross-wave TLP covers the L2 latency instead.
// Target: <=128 unified regs/wave -> __launch_bounds__(256,4) WITHOUT spill
// (round 1's (256,5) forced a ~50-reg spill: 600 MB scratch traffic).
// Numerics identical to round 0 (absmax must reproduce 0.001037598).
// ---------------------------------------------------------------------------
__global__ __launch_bounds__(256, 4)
void fused_mlp_kernel(const float* __restrict__ Abuf, const float* __restrict__ Bbuf,
                      const float* __restrict__ W2f4,  // packed bf16 frags, half-major
                      const float* __restrict__ b2, const float* __restrict__ W3,
                      const float* __restrict__ b3, float* __restrict__ out) {
  __shared__ __align__(16) short s_w2[HID * HID];  // 32 KB, both halves

  int tid = threadIdx.x;
  int w = tid >> 6, l = tid & 63, r = l & 15, q = l >> 4;

  // async stage: 8 x 16B per thread, wave-linear (lds dest = uniform base +
  // lane*16, global src = per-lane) — exactly global_load_lds's contract.
  {
    const float4v* wsrc = (const float4v*)W2f4;
    int wb = tid & 192;                       // w*64, wave-uniform
#pragma unroll
    for (int t = 0; t < 8; ++t) {
      __builtin_amdgcn_global_load_lds(
          (const __attribute__((address_space(1))) void*)(wsrc + t * 256 + tid),
          (__attribute__((address_space(3))) void*)(s_w2 + (t * 256 + wb) * 8),
          16, 0, 0);
    }
  }

  int bi = (blockIdx.x >> 6) << 3;
  int bj = (blockIdx.x & 63) << 4;

  const float* Ap  = Abuf + (bj + r) * HID + q * 8;       // A'[j=bj+r]
  const float* Bp0 = Bbuf + (bi + 2 * w) * HID + q * 8;   // B[i0]
  const float* Bp1 = Bp0 + HID;                           // B[i1]

  short8 afs[4][2];                 // h1 frag stash: [kt][p], 32 VGPRs
  float4v s0 = {0.f, 0.f, 0.f, 0.f};
  float4v s1 = {0.f, 0.f, 0.f, 0.f};
  float4v acc[2][4];

  __syncthreads();                  // drains vmcnt: s_w2 fully staged

  // ---------------- pass 0: g in [0,64) ----------------
#pragma unroll
  for (int nt = 0; nt < 4; ++nt) {
    float4v bv = *(const float4v*)(b2 + nt * 16 + q * 4);
    acc[0][nt] = bv;
    acc[1][nt] = bv;
  }

#pragma unroll
  for (int kt = 0; kt < 4; ++kt) {
    int off = kt * 32;
    float4v ca0  = *(const float4v*)(Ap + off);
    float4v ca1  = *(const float4v*)(Ap + off + 4);
    float4v cb00 = *(const float4v*)(Bp0 + off);
    float4v cb01 = *(const float4v*)(Bp0 + off + 4);
    float4v cb10 = *(const float4v*)(Bp1 + off);
    float4v cb11 = *(const float4v*)(Bp1 + off + 4);

    short8 af0 = to_bf16x8(gelu4(ca0 + cb00), gelu4(ca1 + cb01));
    short8 af1 = to_bf16x8(gelu4(ca0 + cb10), gelu4(ca1 + cb11));
    afs[kt][0] = af0;
    afs[kt][1] = af1;

    const short8* wrow = (const short8*)s_w2 + kt * 256 + l;   // half 0
#pragma unroll
    for (int nt = 0; nt < 4; ++nt) {
      short8 wf = wrow[nt * 64];        // stride-16B, conflict-free
      acc[0][nt] = mfma16(wf, af0, acc[0][nt]);
      acc[1][nt] = mfma16(wf, af1, acc[1][nt]);
    }
  }

#pragma unroll
  for (int nt = 0; nt < 4; ++nt) {
    float4v wv = *(const float4v*)(W3 + nt * 16 + q * 4);
    s0 = s0 + gelu4(acc[0][nt]) * wv;
    s1 = s1 + gelu4(acc[1][nt]) * wv;
  }

  // ---------------- pass 1: g in [64,128) — stash replay, no gelu/VMEM ----
#pragma unroll
  for (int nt = 0; nt < 4; ++nt) {
    float4v bv = *(const float4v*)(b2 + (nt + 4) * 16 + q * 4);
    acc[0][nt] = bv;
    acc[1][nt] = bv;
  }
#pragma unroll
  for (int kt = 0; kt < 4; ++kt) {
    short8 af0 = afs[kt][0];
    short8 af1 = afs[kt][1];
    const short8* wrow = (const short8*)s_w2 + 1024 + kt * 256 + l;  // half 1
#pragma unroll
    for (int nt = 0; nt < 4; ++nt) {
      short8 wf = wrow[nt * 64];
      acc[0][nt] = mfma16(wf, af0, acc[0][nt]);
      acc[1][nt] = mfma16(wf, af1, acc[1][nt]);
    }
  }
#pragma unroll
  for (int nt = 0; nt < 4; ++nt) {
    float4v wv = *(const float4v*)(W3 + (nt + 4) * 16 + q * 4);
    s0 = s0 + gelu4(acc[0][nt]) * wv;
    s1 = s1 + gelu4(acc[1][nt]) * wv;
  }

  // reduce + store
  float bias3 = b3[0];
  float sc0 = s0[0] + s0[1] + s0[2] + s0[3];
  float sc1 = s1[0] + s1[1] + s1[2] + s1[3];
  sc0 += __shfl_xor(sc0, 16, 64);
  sc0 += __shfl_xor(sc0, 32, 64);
  sc1 += __shfl_xor(sc1, 16, 64);
  sc1 += __shfl_xor(sc1, 32, 64);
  if (l < 16) {
    out[(bi + 2 * w) * NN + bj + l]     = sc0 + bias3;
    out[(bi + 2 * w + 1) * NN + bj + l] = sc1 + bias3;
  }
}

extern "C" void kernel_launch(void* const* d_in, const int* in_sizes, int n_in,
                              void* d_out, int out_size, void* d_ws, size_t ws_size,
                              hipStream_t stream) {
  const float* z1 = (const float*)d_in[0];
  const float* z2 = (const float*)d_in[1];
  const float* W1 = (const float*)d_in[2];
  const float* b1 = (const float*)d_in[3];
  const float* W2 = (const float*)d_in[4];
  const float* b2 = (const float*)d_in[5];
  const float* W3 = (const float*)d_in[6];
  const float* b3 = (const float*)d_in[7];
  float* out = (float*)d_out;

  float* Abuf = (float*)d_ws;                                // 512 KB
  float* Bbuf = Abuf + NN * HID;                             // 512 KB
  unsigned short* W2f = (unsigned short*)(Bbuf + NN * HID);  // 32 KB

  prep_kernel<<<264, 256, 0, stream>>>(z1, z2, W1, b1, W2, Abuf, Bbuf, W2f);
  fused_mlp_kernel<<<(NN / 8) * (NN / 16), 256, 0, stream>>>(
      Abuf, Bbuf, (const float*)W2f, b2, W3, b3, out);
}

// Round 5
// 157.339 us; speedup vs baseline: 1.4436x; 1.0098x over previous
//
#include <hip/hip_runtime.h>

#define NN  1024
#define EMB 128
#define HID 128

typedef __attribute__((ext_vector_type(2))) float float2v;
typedef __attribute__((ext_vector_type(4))) float float4v;
typedef __attribute__((ext_vector_type(8))) float float8v;
typedef __attribute__((ext_vector_type(8))) short short8;
typedef __attribute__((ext_vector_type(4))) __bf16 bf16x4;
typedef __attribute__((ext_vector_type(8))) __bf16 bf16x8;

__device__ __forceinline__ float2v lo2(float4v v) { float2v r; r[0] = v[0]; r[1] = v[1]; return r; }
__device__ __forceinline__ float2v hi2(float4v v) { float2v r; r[0] = v[2]; r[1] = v[3]; return r; }

__device__ __forceinline__ short8 to_bf16x8_pk(float2v al, float2v ah, float2v bl, float2v bh) {
  float8v f = {al[0], al[1], ah[0], ah[1], bl[0], bl[1], bh[0], bh[1]};
  bf16x8 r = __builtin_convertvector(f, bf16x8);   // v_cvt_pk_bf16_f32 x4
  return __builtin_bit_cast(short8, r);
}

__device__ __forceinline__ void store_bf16x4(short* p, float4v v) {
  bf16x4 r = __builtin_convertvector(v, bf16x4);
  *(bf16x4*)p = r;
}

// tanh-form GELU on 4 elements as 2x float2v halves, NO inline asm: plain
// vector C arithmetic so the backend can select v_pk_*_f32 (gfx90a+ packed
// fp32) with guaranteed-correct encodings. Same op graph as round 0
// (absmax-identical): ONE v_rcp per 4 elements via shared reciprocal.
// d_i = 1+2^y >= 1, |x|<4.5 => product < 2^80: no overflow.
__device__ __forceinline__ void gelu4pk(float2v xl, float2v xh,
                                        float2v& ol, float2v& oh) {
  float2v x2l = xl * xl;
  float2v x2h = xh * xh;
  float2v tl = x2l * 0.1029432f + 2.3022086f;  // 2*sqrt(2/pi)*log2e*(1+0.044715x^2)
  float2v th = x2h * 0.1029432f + 2.3022086f;
  float2v yl = xl * tl;
  float2v yh = xh * th;
  float2v el, eh;
  el[0] = __builtin_amdgcn_exp2f(yl[0]);
  el[1] = __builtin_amdgcn_exp2f(yl[1]);
  eh[0] = __builtin_amdgcn_exp2f(yh[0]);
  eh[1] = __builtin_amdgcn_exp2f(yh[1]);
  float2v dl = el + 1.0f;
  float2v dh = eh + 1.0f;
  float p01 = dl[0] * dl[1];
  float p23 = dh[0] * dh[1];
  float rall = __builtin_amdgcn_rcpf(p01 * p23);
  float r01 = p23 * rall;                      // 1/(d0*d1)
  float r23 = p01 * rall;                      // 1/(d2*d3)
  float2v rvl, rvh;
  rvl[0] = dl[1] * r01;
  rvl[1] = dl[0] * r01;
  rvh[0] = dh[1] * r23;
  rvh[1] = dh[0] * r23;
  ol = xl - xl * rvl;                          // x*sigmoid(2*inner)
  oh = xh - xh * rvh;
}

__device__ __forceinline__ float4v mfma16(short8 a, short8 b, float4v c) {
  return __builtin_amdgcn_mfma_f32_16x16x32_bf16(a, b, c, 0, 0, 0);
}

// ---------------------------------------------------------------------------
// prep: blocks 0..127  -> Abuf[j, hh*64..+63] = z1[j,:]·W1a[g,:] + b1 (16 j x 64 g)
//       blocks 128..255-> Bbuf[i, hh*64..+63] = z2[i,:]·W1b[g,:]
//       blocks 256..263-> W2f: bf16(W2) pre-swizzled into MFMA frag order,
//                         half-major: half p = g-range [64p,64p+64) contiguous.
// ---------------------------------------------------------------------------
__global__ __launch_bounds__(256)
void prep_kernel(const float* __restrict__ z1, const float* __restrict__ z2,
                 const float* __restrict__ W1, const float* __restrict__ b1,
                 const float* __restrict__ W2,
                 float* __restrict__ Abuf, float* __restrict__ Bbuf,
                 unsigned short* __restrict__ W2f) {
  int blk = blockIdx.x, tid = threadIdx.x;
  if (blk < 256) {
    int which = blk >> 7;                 // 0: A (z1,W1a,+b1)  1: B (z2,W1b)
    int j0 = ((blk & 127) >> 1) << 4;     // 16-row tile
    int hh = blk & 1;                     // h-half (64 g)
    const float* z = which ? z2 : z1;
    __shared__ __align__(16) short zf[4 * 64 * 8];    // 4 KB  z a-frags
    __shared__ __align__(16) short w1f[16 * 64 * 8];  // 16 KB W1 b-frags

#pragma unroll
    for (int p = 0; p < 2; ++p) {
      int u = p * 256 + tid;
      int row = u >> 5;                   // 0..15
      int c = (u & 31) * 4;               // 0..124
      float4v v = *(const float4v*)(z + (j0 + row) * EMB + c);
      int kt = c >> 5;
      int lane = ((c >> 3) & 3) * 16 + row;
      store_bf16x4(zf + (kt * 64 + lane) * 8 + (c & 7), v);
    }
    {
      const float* wbase = W1 + (hh * 64) * (2 * EMB) + which * EMB;
#pragma unroll
      for (int p = 0; p < 8; ++p) {
        int u = p * 256 + tid;
        int grow = u >> 5;                // 0..63
        int c = (u & 31) * 4;
        float4v v = *(const float4v*)(wbase + grow * (2 * EMB) + c);
        int kt = c >> 5;
        int ntl = grow >> 4;              // 0..3
        int lane = ((c >> 3) & 3) * 16 + (grow & 15);
        store_bf16x4(w1f + ((kt * 4 + ntl) * 64 + lane) * 8 + (c & 7), v);
      }
    }
    __syncthreads();

    int w = tid >> 6, l = tid & 63, r = l & 15, q = l >> 4;
    float4v acc = {};
#pragma unroll
    for (int kt = 0; kt < 4; ++kt) {
      short8 az = *(const short8*)(zf + (kt * 64 + l) * 8);
      short8 bf = *(const short8*)(w1f + ((kt * 4 + w) * 64 + l) * 8);
      acc = mfma16(az, bf, acc);
    }
    int gg = hh * 64 + w * 16 + r;
    float ba = which ? 0.0f : b1[gg];
    float* dstp = which ? Bbuf : Abuf;
#pragma unroll
    for (int reg = 0; reg < 4; ++reg)
      dstp[(j0 + q * 4 + reg) * HID + gg] = acc[reg] + ba;
  } else {
    // W2f swizzle: coalesced dwordx4 reads, scattered bf16 writes.
    // Half-major layout: half p = nt>>2 at [p*8192, p*8192+8192) shorts,
    // within a half: ((kt*4 + (nt&3))*64 + lane)*8 + (h&7).
    int s0 = (blk - 256) * 2048 + tid * 8;
    float4v v0 = *(const float4v*)(W2 + s0);
    float4v v1 = *(const float4v*)(W2 + s0 + 4);
    float vals[8] = {v0[0], v0[1], v0[2], v0[3], v1[0], v1[1], v1[2], v1[3]};
#pragma unroll
    for (int j = 0; j < 8; ++j) {
      int s = s0 + j;
      int g = s >> 7;
      int h = s & 127;
      int kt = h >> 5;
      int nt = g >> 4;
      int p = nt >> 2;
      int lane = ((h >> 3) & 3) * 16 + (g & 15);
      int dst = p * 8192 + ((kt * 4 + (nt & 3)) * 64 + lane) * 8 + (h & 7);
      unsigned u = __float_as_uint(vals[j]);
      W2f[dst] = (unsigned short)((u + 0x7FFFu + ((u >> 16) & 1u)) >> 16);  // RNE
    }
  }
}

// ---------------------------------------------------------------------------
// main: one block = 8i x 16j tile, 256 threads (4 waves), wave owns 2 i-rows.
// Swapped operands: D[g][pair] = W2 · h1^T.  TWO-PASS g-split (stash replay).
// Round-5 = round-4's plan with ZERO inline asm:
//   * gelu/input-adds/epilogue in float2v native arithmetic -> backend can
//     select v_pk_*_f32 (gfx950 has packed fp32) with correct encodings.
//     Round 3/4's hand-rolled VOP3P asm produced NaN; compiler-generated
//     pk ops carry no such risk (worst case: scalarized = round-0 parity).
//   * memory structure = exactly the proven pieces: round-2 async
//     global_load_lds W2 staging + round-0 post-barrier kt0 preload with
//     intra-loop next-kt prefetch.
// Numerics: identical op graph to round 0 (absmax ~0.001037598).
// ---------------------------------------------------------------------------
__global__ __launch_bounds__(256, 4)
void fused_mlp_kernel(const float* __restrict__ Abuf, const float* __restrict__ Bbuf,
                      const float* __restrict__ W2f4,  // packed bf16 frags, half-major
                      const float* __restrict__ b2, const float* __restrict__ W3,
                      const float* __restrict__ b3, float* __restrict__ out) {
  __shared__ __align__(16) short s_w2[HID * HID];  // 32 KB, both halves

  int tid = threadIdx.x;
  int w = tid >> 6, l = tid & 63, r = l & 15, q = l >> 4;

  // async stage: 8 x 16B per thread, wave-linear dest — global_load_lds's
  // exact contract (uniform LDS base + lane*16; per-lane global src).
  {
    const float4v* wsrc = (const float4v*)W2f4;
    int wb = tid & 192;                       // wave-uniform base
#pragma unroll
    for (int t = 0; t < 8; ++t) {
      __builtin_amdgcn_global_load_lds(
          (const __attribute__((address_space(1))) void*)(wsrc + t * 256 + tid),
          (__attribute__((address_space(3))) void*)(s_w2 + (t * 256 + wb) * 8),
          16, 0, 0);
    }
  }

  int bi = (blockIdx.x >> 6) << 3;
  int bj = (blockIdx.x & 63) << 4;

  const float* Ap  = Abuf + (bj + r) * HID + q * 8;       // A'[j=bj+r]
  const float* Bp0 = Bbuf + (bi + 2 * w) * HID + q * 8;   // B[i0]
  const float* Bp1 = Bp0 + HID;                           // B[i1]

  short8 afs[4][2];                 // h1 frag stash: [kt][p], 32 VGPRs
  float2v s0l = {0.f, 0.f}, s0h = {0.f, 0.f};
  float2v s1l = {0.f, 0.f}, s1h = {0.f, 0.f};
  float4v acc[2][4];

  __syncthreads();                  // drains vmcnt: s_w2 fully staged

  // ---------------- pass 0: g in [0,64) ----------------
#pragma unroll
  for (int nt = 0; nt < 4; ++nt) {
    float4v bv = *(const float4v*)(b2 + nt * 16 + q * 4);
    acc[0][nt] = bv;
    acc[1][nt] = bv;
  }

  // preload kt=0 globals (post-barrier, round-0 structure)
  float4v a0  = *(const float4v*)(Ap);
  float4v a1  = *(const float4v*)(Ap + 4);
  float4v b00 = *(const float4v*)(Bp0);
  float4v b01 = *(const float4v*)(Bp0 + 4);
  float4v b10 = *(const float4v*)(Bp1);
  float4v b11 = *(const float4v*)(Bp1 + 4);

#pragma unroll
  for (int kt = 0; kt < 4; ++kt) {
    float4v ca0 = a0, ca1 = a1, cb00 = b00, cb01 = b01, cb10 = b10, cb11 = b11;
    if (kt < 3) {                       // issue next-kt loads before gelu chain
      int off = (kt + 1) * 32;
      a0  = *(const float4v*)(Ap + off);
      a1  = *(const float4v*)(Ap + off + 4);
      b00 = *(const float4v*)(Bp0 + off);
      b01 = *(const float4v*)(Bp0 + off + 4);
      b10 = *(const float4v*)(Bp1 + off);
      b11 = *(const float4v*)(Bp1 + off + 4);
    }
    float2v g0l, g0h, g1l, g1h;
    gelu4pk(lo2(ca0) + lo2(cb00), hi2(ca0) + hi2(cb00), g0l, g0h);
    gelu4pk(lo2(ca1) + lo2(cb01), hi2(ca1) + hi2(cb01), g1l, g1h);
    short8 af0 = to_bf16x8_pk(g0l, g0h, g1l, g1h);
    gelu4pk(lo2(ca0) + lo2(cb10), hi2(ca0) + hi2(cb10), g0l, g0h);
    gelu4pk(lo2(ca1) + lo2(cb11), hi2(ca1) + hi2(cb11), g1l, g1h);
    short8 af1 = to_bf16x8_pk(g0l, g0h, g1l, g1h);
    afs[kt][0] = af0;
    afs[kt][1] = af1;

    const short8* wrow = (const short8*)s_w2 + kt * 256 + l;   // half 0
#pragma unroll
    for (int nt = 0; nt < 4; ++nt) {
      short8 wf = wrow[nt * 64];        // stride-16B, conflict-free
      acc[0][nt] = mfma16(wf, af0, acc[0][nt]);
      acc[1][nt] = mfma16(wf, af1, acc[1][nt]);
    }
  }

#pragma unroll
  for (int nt = 0; nt < 4; ++nt) {
    float4v wv = *(const float4v*)(W3 + nt * 16 + q * 4);
    float2v g0l, g0h, g1l, g1h;
    gelu4pk(lo2(acc[0][nt]), hi2(acc[0][nt]), g0l, g0h);
    gelu4pk(lo2(acc[1][nt]), hi2(acc[1][nt]), g1l, g1h);
    s0l = s0l + g0l * lo2(wv);
    s0h = s0h + g0h * hi2(wv);
    s1l = s1l + g1l * lo2(wv);
    s1h = s1h + g1h * hi2(wv);
  }

  // ---------------- pass 1: g in [64,128) — stash replay, no gelu/VMEM ----
#pragma unroll
  for (int nt = 0; nt < 4; ++nt) {
    float4v bv = *(const float4v*)(b2 + (nt + 4) * 16 + q * 4);
    acc[0][nt] = bv;
    acc[1][nt] = bv;
  }
#pragma unroll
  for (int kt = 0; kt < 4; ++kt) {
    short8 af0 = afs[kt][0];
    short8 af1 = afs[kt][1];
    const short8* wrow = (const short8*)s_w2 + 1024 + kt * 256 + l;  // half 1
#pragma unroll
    for (int nt = 0; nt < 4; ++nt) {
      short8 wf = wrow[nt * 64];
      acc[0][nt] = mfma16(wf, af0, acc[0][nt]);
      acc[1][nt] = mfma16(wf, af1, acc[1][nt]);
    }
  }
#pragma unroll
  for (int nt = 0; nt < 4; ++nt) {
    float4v wv = *(const float4v*)(W3 + (nt + 4) * 16 + q * 4);
    float2v g0l, g0h, g1l, g1h;
    gelu4pk(lo2(acc[0][nt]), hi2(acc[0][nt]), g0l, g0h);
    gelu4pk(lo2(acc[1][nt]), hi2(acc[1][nt]), g1l, g1h);
    s0l = s0l + g0l * lo2(wv);
    s0h = s0h + g0h * hi2(wv);
    s1l = s1l + g1l * lo2(wv);
    s1h = s1h + g1h * hi2(wv);
  }

  // reduce + store
  float bias3 = b3[0];
  float sc0 = s0l[0] + s0l[1] + s0h[0] + s0h[1];
  float sc1 = s1l[0] + s1l[1] + s1h[0] + s1h[1];
  sc0 += __shfl_xor(sc0, 16, 64);
  sc0 += __shfl_xor(sc0, 32, 64);
  sc1 += __shfl_xor(sc1, 16, 64);
  sc1 += __shfl_xor(sc1, 32, 64);
  if (l < 16) {
    out[(bi + 2 * w) * NN + bj + l]     = sc0 + bias3;
    out[(bi + 2 * w + 1) * NN + bj + l] = sc1 + bias3;
  }
}

extern "C" void kernel_launch(void* const* d_in, const int* in_sizes, int n_in,
                              void* d_out, int out_size, void* d_ws, size_t ws_size,
                              hipStream_t stream) {
  const float* z1 = (const float*)d_in[0];
  const float* z2 = (const float*)d_in[1];
  const float* W1 = (const float*)d_in[2];
  const float* b1 = (const float*)d_in[3];
  const float* W2 = (const float*)d_in[4];
  const float* b2 = (const float*)d_in[5];
  const float* W3 = (const float*)d_in[6];
  const float* b3 = (const float*)d_in[7];
  float* out = (float*)d_out;

  float* Abuf = (float*)d_ws;                                // 512 KB
  float* Bbuf = Abuf + NN * HID;                             // 512 KB
  unsigned short* W2f = (unsigned short*)(Bbuf + NN * HID);  // 32 KB

  prep_kernel<<<264, 256, 0, stream>>>(z1, z2, W1, b1, W2, Abuf, Bbuf, W2f);
  fused_mlp_kernel<<<(NN / 8) * (NN / 16), 256, 0, stream>>>(
      Abuf, Bbuf, (const float*)W2f, b2, W3, b3, out);
}